// Round 14
// baseline (75.850 us; speedup 1.0000x reference)
//
#include <hip/hip_runtime.h>
#include <hip/hip_bf16.h>
#include <math.h>

#define L 128
#define B 4
#define H 768
#define LN_EPS 1e-5f
#define XROWS 272            // [p1:0..127 | p2:128..255 | pg:256 | unused tail]

typedef __attribute__((ext_vector_type(8))) short short8;
typedef __attribute__((ext_vector_type(4))) float f32x4;
typedef __attribute__((ext_vector_type(16))) float f32x16;

static __device__ __forceinline__ unsigned f2bfu(float f) {
    unsigned u = __float_as_uint(f);
    return (u + 0x7FFFu + ((u >> 16) & 1u)) >> 16;
}
static __device__ __forceinline__ uint2 pk4(float4 v) {
    uint2 o;
    o.x = f2bfu(v.x) | (f2bfu(v.y) << 16);
    o.y = f2bfu(v.z) | (f2bfu(v.w) << 16);
    return o;
}
static __device__ __forceinline__ unsigned short f2b(float f) {
    union { __hip_bfloat16 h; unsigned short u; } cv;
    cv.h = __float2bfloat16(f);
    return cv.u;
}
static __device__ __forceinline__ float4 unpk4(uint2 p) {
    return make_float4(__uint_as_float(p.x << 16),
                       __uint_as_float(p.x & 0xffff0000u),
                       __uint_as_float(p.y << 16),
                       __uint_as_float(p.y & 0xffff0000u));
}
static __device__ __forceinline__ unsigned fkey(float x) {
    unsigned u = __float_as_uint(x);
    return (u >> 31) ? ~u : (u | 0x80000000u);
}

// ---------------------------------------------------------------------------
// kConv: all fp32->bf16 packing, coalesced READS + scattered 16B writes.
// ---------------------------------------------------------------------------
__global__ __launch_bounds__(256) void kConv(const float* __restrict__ h_re,
                                             const float* __restrict__ h_share,
                                             const float* __restrict__ r_w,
                                             const float* __restrict__ hid_w,
                                             const float* __restrict__ rel_w,
                                             unsigned short* __restrict__ apack,
                                             unsigned short* __restrict__ wpackA,
                                             unsigned short* __restrict__ wpackB,
                                             unsigned short* __restrict__ rwb2,
                                             unsigned int* __restrict__ gmax) {
    int t = blockIdx.x * 256 + threadIdx.x;
    if (t >= 397056) return;
    if (t < 98304) {                          // apack: Acat=[h_share|h_re]
        int m = t / 192, oct = t % 192, k = oct * 8;
        const float* src = (k < 768) ? (h_share + (size_t)m * 768 + k)
                                     : (h_re + (size_t)m * 768 + k - 768);
        float4 x = *(const float4*)src, y = *(const float4*)(src + 4);
        int mt = m >> 4, lr = m & 15, ks = k >> 5, lq = (k >> 3) & 3;
        uint2* dst = (uint2*)(apack + (((size_t)mt * 48 + ks) * 64 + lq * 16 + lr) * 8);
        dst[0] = pk4(x); dst[1] = pk4(y);
    } else if (t < 245760) {                  // wpackA: r_w rows
        int t2 = t - 98304;
        int n = t2 / 192, oct = t2 % 192, k = oct * 8;
        const float* src = r_w + (size_t)n * 1536 + k;
        float4 x = *(const float4*)src, y = *(const float4*)(src + 4);
        int nt = n >> 4, lr = n & 15, ks = k >> 5, lq = (k >> 3) & 3;
        uint2* dst = (uint2*)(wpackA + (((size_t)nt * 48 + ks) * 64 + lq * 16 + lr) * 8);
        dst[0] = pk4(x); dst[1] = pk4(y);
    } else if (t < 393216) {                  // wpackB: hid_w rows (w1|w2)
        int t3 = t - 245760;
        int n = t3 / 96, oct = t3 % 96, k = oct * 8;
        int half = (n >= 768) ? 1 : 0;
        const float* src = hid_w + (size_t)(n - half * 768) * 2304 + half * 768 + k;
        float4 x = *(const float4*)src, y = *(const float4*)(src + 4);
        int nt = n >> 4, lr = n & 15, ks = k >> 5, lq = (k >> 3) & 3;
        uint2* dst = (uint2*)(wpackB + (((size_t)nt * 24 + ks) * 64 + lq * 16 + lr) * 8);
        dst[0] = pk4(x); dst[1] = pk4(y);
    } else if (t < 396288) {                  // rwb2: B-frag-linear rel_w (32x32x16)
        int t4 = t - 393216;                  // 0..3071: (s, lane)
        int s = t4 >> 6, l = t4 & 63;
        int row = l & 31;
        uint2 o0 = make_uint2(0u, 0u), o1 = o0;
        if (row < 24) {
            const float* src = rel_w + (size_t)row * 768 + s * 16 + (l >> 5) * 8;
            o0 = pk4(*(const float4*)src);
            o1 = pk4(*(const float4*)(src + 4));
        }
        uint2* dst = (uint2*)(rwb2 + (size_t)t4 * 8);
        dst[0] = o0; dst[1] = o1;
    } else {                                  // gmax zero (768 scalars)
        int t6 = t - 396288;
        gmax[t6] = 0u;
        gmax[768 + t6] = 0u;
        gmax[1536 + t6] = 0u;
        gmax[2304 + t6] = 0u;
    }
}

// ---------------------------------------------------------------------------
// kGemm: 4-wave blocks, one 32x32 tile per block, K split 4 ways across waves,
// LDS reduce, epilogue on wave 0. (r13, proven −7.6 us)
// ---------------------------------------------------------------------------
template<int KSW>
static __device__ __forceinline__ void gemm_steps(const unsigned short* __restrict__ a0p,
                                                  const unsigned short* __restrict__ a1p,
                                                  const unsigned short* __restrict__ w0p,
                                                  const unsigned short* __restrict__ w1p,
                                                  f32x4 acc[2][2]) {
#pragma unroll
    for (int s = 0; s < KSW; s++) {
        short8 a0 = *(const short8*)(a0p + (size_t)s * 512);
        short8 a1 = *(const short8*)(a1p + (size_t)s * 512);
        short8 w0 = *(const short8*)(w0p + (size_t)s * 512);
        short8 w1 = *(const short8*)(w1p + (size_t)s * 512);
        acc[0][0] = __builtin_amdgcn_mfma_f32_16x16x32_bf16(a0, w0, acc[0][0], 0, 0, 0);
        acc[0][1] = __builtin_amdgcn_mfma_f32_16x16x32_bf16(a0, w1, acc[0][1], 0, 0, 0);
        acc[1][0] = __builtin_amdgcn_mfma_f32_16x16x32_bf16(a1, w0, acc[1][0], 0, 0, 0);
        acc[1][1] = __builtin_amdgcn_mfma_f32_16x16x32_bf16(a1, w1, acc[1][1], 0, 0, 0);
    }
}

__global__ __launch_bounds__(256) void kGemm(const unsigned short* __restrict__ apack,
                                             const unsigned short* __restrict__ wpackA,
                                             const unsigned short* __restrict__ wpackB,
                                             unsigned int* __restrict__ gmax,
                                             unsigned short* __restrict__ xb16) {
    __shared__ float red[4][4][64][4];        // 16 KB
    int id = blockIdx.x;
    int tid = threadIdx.x, lane = tid & 63, wv = tid >> 6;
    int lq = lane >> 4, lr = lane & 15;
    bool isA = id < 384;
    f32x4 acc[2][2] = {{{0.f,0.f,0.f,0.f},{0.f,0.f,0.f,0.f}},
                       {{0.f,0.f,0.f,0.f},{0.f,0.f,0.f,0.f}}};
    int mt0, nt0;
    if (isA) {
        mt0 = (id / 24) * 2; nt0 = (id % 24) * 2;
        const unsigned short* a0p = apack + ((size_t)mt0 * 48 + wv * 12) * 512 + lane * 8;
        const unsigned short* w0p = wpackA + ((size_t)nt0 * 48 + wv * 12) * 512 + lane * 8;
        gemm_steps<12>(a0p, a0p + 48 * 512, w0p, w0p + 48 * 512, acc);
    } else {
        int id2 = id - 384;
        mt0 = (id2 / 48) * 2; nt0 = (id2 % 48) * 2;
        const unsigned short* a0p = apack + ((size_t)mt0 * 48 + 24 + wv * 6) * 512 + lane * 8;
        const unsigned short* w0p = wpackB + ((size_t)nt0 * 24 + wv * 6) * 512 + lane * 8;
        gemm_steps<6>(a0p, a0p + 48 * 512, w0p, w0p + 24 * 512, acc);
    }
#pragma unroll
    for (int mi = 0; mi < 2; mi++)
#pragma unroll
        for (int ni = 0; ni < 2; ni++)
            *(f32x4*)&red[wv][mi * 2 + ni][lane][0] = acc[mi][ni];
    __syncthreads();
    if (wv != 0) return;

    f32x4 s2[2][2];
#pragma unroll
    for (int mi = 0; mi < 2; mi++)
#pragma unroll
        for (int ni = 0; ni < 2; ni++) {
            f32x4 v = *(f32x4*)&red[0][mi * 2 + ni][lane][0];
#pragma unroll
            for (int w = 1; w < 4; w++) {
                f32x4 u = *(f32x4*)&red[w][mi * 2 + ni][lane][0];
                v[0] += u[0]; v[1] += u[1]; v[2] += u[2]; v[3] += u[3];
            }
            s2[mi][ni] = v;
        }

    if (isA) {
#pragma unroll
        for (int ni = 0; ni < 2; ni++)
#pragma unroll
            for (int q = 0; q < 4; q++) {
                float mx = fmaxf(s2[0][ni][q], s2[1][ni][q]);
                mx = fmaxf(mx, __shfl_xor(mx, 16, 64));
                mx = fmaxf(mx, __shfl_xor(mx, 32, 64));
                if (lq == 0) {
                    int n = (nt0 + ni) * 16 + lr;
                    atomicMax(&gmax[q * 768 + n], fkey(mx));
                }
            }
    } else {
#pragma unroll
        for (int mi = 0; mi < 2; mi++)
#pragma unroll
            for (int ni = 0; ni < 2; ni++)
#pragma unroll
                for (int q = 0; q < 4; q++) {
                    int m = (mt0 + mi) * 16 + lq * 4 + q;
                    int n = (nt0 + ni) * 16 + lr;
                    int b = m & 3, l = m >> 2;
                    size_t row = (n < 768) ? (size_t)l : (size_t)(128 + l);
                    int col = (n < 768) ? n : n - 768;
                    xb16[((size_t)b * XROWS + row) * 768 + col] = f2b(s2[mi][ni][q]);
                }
    }
}

// ---------------------------------------------------------------------------
// kPg: decode gmax -> g = tanh(max+r_b), pg = g.w3 + hid_b -> xb16 row 256.
// grid (12,4). (Gram packing removed: kC computes stats inline now.)
// ---------------------------------------------------------------------------
__global__ __launch_bounds__(256) void kPg(const unsigned int* __restrict__ gmax,
                                           const float* __restrict__ r_b,
                                           const float* __restrict__ hid_w,
                                           const float* __restrict__ hid_b,
                                           unsigned short* __restrict__ xb16) {
    __shared__ float sg[768];
    __shared__ float sp[4][64];
    int kt = blockIdx.x, b = blockIdx.y, tid = threadIdx.x;
    for (int v = tid; v < 768; v += 256) {
        unsigned key = gmax[b * 768 + v];
        unsigned bits = (key & 0x80000000u) ? (key & 0x7FFFFFFFu) : ~key;
        sg[v] = tanhf(__uint_as_float(bits) + r_b[v]);
    }
    __syncthreads();
    int kk = tid & 63, hc = tid >> 6;
    int k = kt * 64 + kk;
    const float4* w4 = (const float4*)hid_w;
    const float4* g4 = (const float4*)sg;
    float acc = 0.f;
    for (int h = hc * 48; h < hc * 48 + 48; h++) {
        float4 gv = g4[h];
        float4 wv = w4[(size_t)k * 576 + 384 + h];
        acc += gv.x * wv.x + gv.y * wv.y + gv.z * wv.z + gv.w * wv.w;
    }
    sp[hc][kk] = acc;
    __syncthreads();
    if (hc == 0) {
        float pgv = sp[0][kk] + sp[1][kk] + sp[2][kk] + sp[3][kk] + hid_b[k];
        xb16[((size_t)b * XROWS + 256) * 768 + k] = f2b(pgv);
    }
}

// ---------------------------------------------------------------------------
// kC: block (i, b, jg) -> 32 j's, 512 thr (8 waves).
// Phase1: per row — compute z = u+v in regs, wave shuffle-reduce s1/s2,
//         normalize+ELU -> zls bf16 [32][780]. (no Gram/D dependency)
// Phase2: one 32x32x16 MFMA chain per wave, K split 8 ways, coalesced B-frags,
//         f32 partial reduce in aliased LDS.
// ---------------------------------------------------------------------------
__global__ __launch_bounds__(512, 6) void kC(const unsigned short* __restrict__ xb16,
                                             const float* __restrict__ ln_g,
                                             const float* __restrict__ ln_b,
                                             const unsigned short* __restrict__ rwb2,
                                             const float* __restrict__ rel_b,
                                             const float* __restrict__ mask,
                                             float* __restrict__ out) {
    __shared__ __align__(16) unsigned char smem[49920];   // 32*780*2
    unsigned short (*zls)[780] = (unsigned short (*)[780])smem;
    int i = blockIdx.x, b = blockIdx.y, j0 = blockIdx.z * 32;
    int tid = threadIdx.x, lane = tid & 63, wave = tid >> 6;

    const uint2* ur = (const uint2*)(xb16 + ((size_t)b * XROWS + i) * 768);
    const uint2* pr = (const uint2*)(xb16 + ((size_t)b * XROWS + 256) * 768);
    const float4* lg4 = (const float4*)ln_g;
    const float4* lb4 = (const float4*)ln_b;
    float4 t1[3], gg[3], bb[3];
#pragma unroll
    for (int s = 0; s < 3; s++) {
        int c = lane + 64 * s;
        float4 x = unpk4(ur[c]), y = unpk4(pr[c]);
        t1[s] = make_float4(x.x + y.x, x.y + y.y, x.z + y.z, x.w + y.w);
        gg[s] = lg4[c];
        bb[s] = lb4[c];
    }

#pragma unroll
    for (int jj = 0; jj < 4; jj++) {
        int j = wave * 4 + jj;
        const uint2* vr2 = (const uint2*)(xb16 + ((size_t)b * XROWS + 128 + j0 + j) * 768);
        float4 z[3];
        float s1 = 0.f, s2 = 0.f;
#pragma unroll
        for (int s = 0; s < 3; s++) {
            float4 vv = unpk4(vr2[lane + 64 * s]);
            vv.x += t1[s].x; vv.y += t1[s].y; vv.z += t1[s].z; vv.w += t1[s].w;
            z[s] = vv;
            s1 += vv.x + vv.y + vv.z + vv.w;
            s2 += vv.x * vv.x + vv.y * vv.y + vv.z * vv.z + vv.w * vv.w;
        }
#pragma unroll
        for (int off = 32; off > 0; off >>= 1) {
            s1 += __shfl_xor(s1, off, 64);
            s2 += __shfl_xor(s2, off, 64);
        }
        float mu = s1 * (1.f / 768.f);
        float rs = rsqrtf(s2 * (1.f / 768.f) - mu * mu + LN_EPS);
        uint2* zrow = (uint2*)&zls[j][0];
#pragma unroll
        for (int s = 0; s < 3; s++) {
            float A0 = rs * gg[s].x, A1 = rs * gg[s].y, A2 = rs * gg[s].z, A3 = rs * gg[s].w;
            float C0 = fmaf(-mu, A0, bb[s].x), C1 = fmaf(-mu, A1, bb[s].y);
            float C2 = fmaf(-mu, A2, bb[s].z), C3 = fmaf(-mu, A3, bb[s].w);
            float z0 = fmaf(z[s].x, A0, C0);
            float z1 = fmaf(z[s].y, A1, C1);
            float z2 = fmaf(z[s].z, A2, C2);
            float z3 = fmaf(z[s].w, A3, C3);
            z0 = fmaxf(z0, __expf(fminf(z0, 0.f)) - 1.f);
            z1 = fmaxf(z1, __expf(fminf(z1, 0.f)) - 1.f);
            z2 = fmaxf(z2, __expf(fminf(z2, 0.f)) - 1.f);
            z3 = fmaxf(z3, __expf(fminf(z3, 0.f)) - 1.f);
            uint2 o;
            o.x = (unsigned)f2b(z0) | ((unsigned)f2b(z1) << 16);
            o.y = (unsigned)f2b(z2) | ((unsigned)f2b(z3) << 16);
            zrow[lane + 64 * s] = o;
        }
    }
    __syncthreads();

    // phase 2: wave kq handles K-steps kq*6..kq*6+5 of 48 (K=768, 16 per step)
    int arow = lane & 31, ahi = lane >> 5;
    f32x16 acc = {0.f,0.f,0.f,0.f, 0.f,0.f,0.f,0.f, 0.f,0.f,0.f,0.f, 0.f,0.f,0.f,0.f};
    const unsigned short* bptr = rwb2 + ((size_t)(wave * 6) * 64 + lane) * 8;
#pragma unroll
    for (int st = 0; st < 6; st++) {
        int s = wave * 6 + st;
        short8 a  = *(const short8*)&zls[arow][s * 16 + ahi * 8];
        short8 bf = *(const short8*)(bptr + (size_t)st * 512);
        acc = __builtin_amdgcn_mfma_f32_32x32x16_bf16(a, bf, acc, 0, 0, 0);
    }
    __syncthreads();
    float* pf = (float*)smem;                 // 8 waves x 1024 f32 = 32 KB
#pragma unroll
    for (int r = 0; r < 16; r++) {
        int row = (r & 3) + 8 * (r >> 2) + 4 * ahi;
        pf[wave * 1024 + row * 32 + arow] = acc[r];
    }
    __syncthreads();

#pragma unroll
    for (int e0 = 0; e0 < 2; e0++) {
        int e = tid + e0 * 512;
        int row = e >> 5, col = e & 31;
        if (col < 24) {
            float v = 0.f;
#pragma unroll
            for (int w = 0; w < 8; w++) v += pf[w * 1024 + e];
            int jgl = j0 + row;
            float mval = mask[i * 4 + b] * mask[jgl * 4 + b];
            out[((size_t)(i * 128 + jgl) * 4 + b) * 24 + col] =
                mval / (1.f + __expf(-(v + rel_b[col])));
        }
    }
}

// ---------------------------------------------------------------------------
extern "C" void kernel_launch(void* const* d_in, const int* in_sizes, int n_in,
                              void* d_out, int out_size, void* d_ws, size_t ws_size,
                              hipStream_t stream) {
    const float* h_re    = (const float*)d_in[0];
    const float* h_share = (const float*)d_in[1];
    const float* mask    = (const float*)d_in[2];
    const float* r_w     = (const float*)d_in[3];
    const float* r_b     = (const float*)d_in[4];
    const float* hid_w   = (const float*)d_in[5];
    const float* hid_b   = (const float*)d_in[6];
    const float* ln_g    = (const float*)d_in[7];
    const float* ln_b    = (const float*)d_in[8];
    const float* rel_w   = (const float*)d_in[9];
    const float* rel_b   = (const float*)d_in[10];
    float* out = (float*)d_out;

    float* ws = (float*)d_ws;
    unsigned short* apack  = (unsigned short*)(ws);             // 393216 f
    unsigned short* wpackA = (unsigned short*)(ws + 393216);    // 589824 f
    unsigned short* wpackB = (unsigned short*)(ws + 983040);    // 589824 f
    unsigned short* xb16   = (unsigned short*)(ws + 1572864);   // 417792 f
    unsigned int*   gmax   = (unsigned int*)(ws + 1990656);     // 3072
    unsigned short* rwb2   = (unsigned short*)(ws + 1993728);   // 12288 f

    kConv<<<1552, 256, 0, stream>>>(h_re, h_share, r_w, hid_w, rel_w,
                                    apack, wpackA, wpackB, rwb2, gmax);
    kGemm<<<1152, 256, 0, stream>>>(apack, wpackA, wpackB, gmax, xb16);
    kPg<<<dim3(12, 4), 256, 0, stream>>>(gmax, r_b, hid_w, hid_b, xb16);
    kC<<<dim3(L, B, 4), 512, 0, stream>>>(xb16, ln_g, ln_b, rwb2, rel_b,
                                          mask, out);
}

// Round 15
// 73.122 us; speedup vs baseline: 1.0373x; 1.0373x over previous
//
#include <hip/hip_runtime.h>
#include <hip/hip_bf16.h>
#include <math.h>

#define L 128
#define B 4
#define H 768
#define LN_EPS 1e-5f
#define XROWS 272            // [p1:0..127 | p2:128..255 | pg:256 | unused tail]

typedef __attribute__((ext_vector_type(8))) short short8;
typedef __attribute__((ext_vector_type(4))) float f32x4;
typedef __attribute__((ext_vector_type(16))) float f32x16;

static __device__ __forceinline__ unsigned f2bfu(float f) {
    unsigned u = __float_as_uint(f);
    return (u + 0x7FFFu + ((u >> 16) & 1u)) >> 16;
}
static __device__ __forceinline__ uint2 pk4(float4 v) {
    uint2 o;
    o.x = f2bfu(v.x) | (f2bfu(v.y) << 16);
    o.y = f2bfu(v.z) | (f2bfu(v.w) << 16);
    return o;
}
static __device__ __forceinline__ unsigned short f2b(float f) {
    union { __hip_bfloat16 h; unsigned short u; } cv;
    cv.h = __float2bfloat16(f);
    return cv.u;
}
static __device__ __forceinline__ float4 unpk4(uint2 p) {
    return make_float4(__uint_as_float(p.x << 16),
                       __uint_as_float(p.x & 0xffff0000u),
                       __uint_as_float(p.y << 16),
                       __uint_as_float(p.y & 0xffff0000u));
}
static __device__ __forceinline__ unsigned fkey(float x) {
    unsigned u = __float_as_uint(x);
    return (u >> 31) ? ~u : (u | 0x80000000u);
}

// ---------------------------------------------------------------------------
// kConv: all fp32->bf16 packing, coalesced READS + scattered 16B writes.
// ---------------------------------------------------------------------------
__global__ __launch_bounds__(256) void kConv(const float* __restrict__ h_re,
                                             const float* __restrict__ h_share,
                                             const float* __restrict__ r_w,
                                             const float* __restrict__ hid_w,
                                             const float* __restrict__ rel_w,
                                             unsigned short* __restrict__ apack,
                                             unsigned short* __restrict__ wpackA,
                                             unsigned short* __restrict__ wpackB,
                                             unsigned short* __restrict__ rwb2,
                                             unsigned int* __restrict__ gmax) {
    int t = blockIdx.x * 256 + threadIdx.x;
    if (t >= 397056) return;
    if (t < 98304) {                          // apack: Acat=[h_share|h_re]
        int m = t / 192, oct = t % 192, k = oct * 8;
        const float* src = (k < 768) ? (h_share + (size_t)m * 768 + k)
                                     : (h_re + (size_t)m * 768 + k - 768);
        float4 x = *(const float4*)src, y = *(const float4*)(src + 4);
        int mt = m >> 4, lr = m & 15, ks = k >> 5, lq = (k >> 3) & 3;
        uint2* dst = (uint2*)(apack + (((size_t)mt * 48 + ks) * 64 + lq * 16 + lr) * 8);
        dst[0] = pk4(x); dst[1] = pk4(y);
    } else if (t < 245760) {                  // wpackA: r_w rows
        int t2 = t - 98304;
        int n = t2 / 192, oct = t2 % 192, k = oct * 8;
        const float* src = r_w + (size_t)n * 1536 + k;
        float4 x = *(const float4*)src, y = *(const float4*)(src + 4);
        int nt = n >> 4, lr = n & 15, ks = k >> 5, lq = (k >> 3) & 3;
        uint2* dst = (uint2*)(wpackA + (((size_t)nt * 48 + ks) * 64 + lq * 16 + lr) * 8);
        dst[0] = pk4(x); dst[1] = pk4(y);
    } else if (t < 393216) {                  // wpackB: hid_w rows (w1|w2)
        int t3 = t - 245760;
        int n = t3 / 96, oct = t3 % 96, k = oct * 8;
        int half = (n >= 768) ? 1 : 0;
        const float* src = hid_w + (size_t)(n - half * 768) * 2304 + half * 768 + k;
        float4 x = *(const float4*)src, y = *(const float4*)(src + 4);
        int nt = n >> 4, lr = n & 15, ks = k >> 5, lq = (k >> 3) & 3;
        uint2* dst = (uint2*)(wpackB + (((size_t)nt * 24 + ks) * 64 + lq * 16 + lr) * 8);
        dst[0] = pk4(x); dst[1] = pk4(y);
    } else if (t < 396288) {                  // rwb2: B-frag-linear rel_w (32x32x16)
        int t4 = t - 393216;                  // 0..3071: (s, lane)
        int s = t4 >> 6, l = t4 & 63;
        int row = l & 31;
        uint2 o0 = make_uint2(0u, 0u), o1 = o0;
        if (row < 24) {
            const float* src = rel_w + (size_t)row * 768 + s * 16 + (l >> 5) * 8;
            o0 = pk4(*(const float4*)src);
            o1 = pk4(*(const float4*)(src + 4));
        }
        uint2* dst = (uint2*)(rwb2 + (size_t)t4 * 8);
        dst[0] = o0; dst[1] = o1;
    } else {                                  // gmax zero (768 scalars)
        int t6 = t - 396288;
        gmax[t6] = 0u;
        gmax[768 + t6] = 0u;
        gmax[1536 + t6] = 0u;
        gmax[2304 + t6] = 0u;
    }
}

// ---------------------------------------------------------------------------
// kGemm: 4-wave blocks, one 32x32 tile per block, K split 4 ways across waves,
// LDS reduce, epilogue on wave 0. (r13, proven −7.6 us)
// ---------------------------------------------------------------------------
template<int KSW>
static __device__ __forceinline__ void gemm_steps(const unsigned short* __restrict__ a0p,
                                                  const unsigned short* __restrict__ a1p,
                                                  const unsigned short* __restrict__ w0p,
                                                  const unsigned short* __restrict__ w1p,
                                                  f32x4 acc[2][2]) {
#pragma unroll
    for (int s = 0; s < KSW; s++) {
        short8 a0 = *(const short8*)(a0p + (size_t)s * 512);
        short8 a1 = *(const short8*)(a1p + (size_t)s * 512);
        short8 w0 = *(const short8*)(w0p + (size_t)s * 512);
        short8 w1 = *(const short8*)(w1p + (size_t)s * 512);
        acc[0][0] = __builtin_amdgcn_mfma_f32_16x16x32_bf16(a0, w0, acc[0][0], 0, 0, 0);
        acc[0][1] = __builtin_amdgcn_mfma_f32_16x16x32_bf16(a0, w1, acc[0][1], 0, 0, 0);
        acc[1][0] = __builtin_amdgcn_mfma_f32_16x16x32_bf16(a1, w0, acc[1][0], 0, 0, 0);
        acc[1][1] = __builtin_amdgcn_mfma_f32_16x16x32_bf16(a1, w1, acc[1][1], 0, 0, 0);
    }
}

__global__ __launch_bounds__(256) void kGemm(const unsigned short* __restrict__ apack,
                                             const unsigned short* __restrict__ wpackA,
                                             const unsigned short* __restrict__ wpackB,
                                             unsigned int* __restrict__ gmax,
                                             unsigned short* __restrict__ xb16) {
    __shared__ float red[4][4][64][4];        // 16 KB
    int id = blockIdx.x;
    int tid = threadIdx.x, lane = tid & 63, wv = tid >> 6;
    int lq = lane >> 4, lr = lane & 15;
    bool isA = id < 384;
    f32x4 acc[2][2] = {{{0.f,0.f,0.f,0.f},{0.f,0.f,0.f,0.f}},
                       {{0.f,0.f,0.f,0.f},{0.f,0.f,0.f,0.f}}};
    int mt0, nt0;
    if (isA) {
        mt0 = (id / 24) * 2; nt0 = (id % 24) * 2;
        const unsigned short* a0p = apack + ((size_t)mt0 * 48 + wv * 12) * 512 + lane * 8;
        const unsigned short* w0p = wpackA + ((size_t)nt0 * 48 + wv * 12) * 512 + lane * 8;
        gemm_steps<12>(a0p, a0p + 48 * 512, w0p, w0p + 48 * 512, acc);
    } else {
        int id2 = id - 384;
        mt0 = (id2 / 48) * 2; nt0 = (id2 % 48) * 2;
        const unsigned short* a0p = apack + ((size_t)mt0 * 48 + 24 + wv * 6) * 512 + lane * 8;
        const unsigned short* w0p = wpackB + ((size_t)nt0 * 24 + wv * 6) * 512 + lane * 8;
        gemm_steps<6>(a0p, a0p + 48 * 512, w0p, w0p + 24 * 512, acc);
    }
#pragma unroll
    for (int mi = 0; mi < 2; mi++)
#pragma unroll
        for (int ni = 0; ni < 2; ni++)
            *(f32x4*)&red[wv][mi * 2 + ni][lane][0] = acc[mi][ni];
    __syncthreads();
    if (wv != 0) return;

    f32x4 s2[2][2];
#pragma unroll
    for (int mi = 0; mi < 2; mi++)
#pragma unroll
        for (int ni = 0; ni < 2; ni++) {
            f32x4 v = *(f32x4*)&red[0][mi * 2 + ni][lane][0];
#pragma unroll
            for (int w = 1; w < 4; w++) {
                f32x4 u = *(f32x4*)&red[w][mi * 2 + ni][lane][0];
                v[0] += u[0]; v[1] += u[1]; v[2] += u[2]; v[3] += u[3];
            }
            s2[mi][ni] = v;
        }

    if (isA) {
#pragma unroll
        for (int ni = 0; ni < 2; ni++)
#pragma unroll
            for (int q = 0; q < 4; q++) {
                float mx = fmaxf(s2[0][ni][q], s2[1][ni][q]);
                mx = fmaxf(mx, __shfl_xor(mx, 16, 64));
                mx = fmaxf(mx, __shfl_xor(mx, 32, 64));
                if (lq == 0) {
                    int n = (nt0 + ni) * 16 + lr;
                    atomicMax(&gmax[q * 768 + n], fkey(mx));
                }
            }
    } else {
#pragma unroll
        for (int mi = 0; mi < 2; mi++)
#pragma unroll
            for (int ni = 0; ni < 2; ni++)
#pragma unroll
                for (int q = 0; q < 4; q++) {
                    int m = (mt0 + mi) * 16 + lq * 4 + q;
                    int n = (nt0 + ni) * 16 + lr;
                    int b = m & 3, l = m >> 2;
                    size_t row = (n < 768) ? (size_t)l : (size_t)(128 + l);
                    int col = (n < 768) ? n : n - 768;
                    xb16[((size_t)b * XROWS + row) * 768 + col] = f2b(s2[mi][ni][q]);
                }
    }
}

// ---------------------------------------------------------------------------
// kPg: decode gmax -> g = tanh(max+r_b), pg = g.w3 + hid_b -> xb16 row 256.
// ---------------------------------------------------------------------------
__global__ __launch_bounds__(256) void kPg(const unsigned int* __restrict__ gmax,
                                           const float* __restrict__ r_b,
                                           const float* __restrict__ hid_w,
                                           const float* __restrict__ hid_b,
                                           unsigned short* __restrict__ xb16) {
    __shared__ float sg[768];
    __shared__ float sp[4][64];
    int kt = blockIdx.x, b = blockIdx.y, tid = threadIdx.x;
    for (int v = tid; v < 768; v += 256) {
        unsigned key = gmax[b * 768 + v];
        unsigned bits = (key & 0x80000000u) ? (key & 0x7FFFFFFFu) : ~key;
        sg[v] = tanhf(__uint_as_float(bits) + r_b[v]);
    }
    __syncthreads();
    int kk = tid & 63, hc = tid >> 6;
    int k = kt * 64 + kk;
    const float4* w4 = (const float4*)hid_w;
    const float4* g4 = (const float4*)sg;
    float acc = 0.f;
    for (int h = hc * 48; h < hc * 48 + 48; h++) {
        float4 gv = g4[h];
        float4 wv = w4[(size_t)k * 576 + 384 + h];
        acc += gv.x * wv.x + gv.y * wv.y + gv.z * wv.z + gv.w * wv.w;
    }
    sp[hc][kk] = acc;
    __syncthreads();
    if (hc == 0) {
        float pgv = sp[0][kk] + sp[1][kk] + sp[2][kk] + sp[3][kk] + hid_b[k];
        xb16[((size_t)b * XROWS + 256) * 768 + k] = f2b(pgv);
    }
}

// ---------------------------------------------------------------------------
// kC: block (i, b, jg) -> 32 j's, 512 thr (8 waves).
// launch_bounds (512, 3): LDS caps at 3 blocks/CU anyway; this gives the
// register allocator ~80 VGPRs (r14's (512,6) forced 40 -> 69MB spill storm).
// Phase1: per row — z = u+v in regs, wave shuffle-reduce s1/s2, LN+ELU ->
//         zls bf16 [32][780]. Phase2: 32x32x16 MFMA, K split 8 ways.
// ---------------------------------------------------------------------------
__global__ __launch_bounds__(512, 3) void kC(const unsigned short* __restrict__ xb16,
                                             const float* __restrict__ ln_g,
                                             const float* __restrict__ ln_b,
                                             const unsigned short* __restrict__ rwb2,
                                             const float* __restrict__ rel_b,
                                             const float* __restrict__ mask,
                                             float* __restrict__ out) {
    __shared__ __align__(16) unsigned char smem[49920];   // 32*780*2
    unsigned short (*zls)[780] = (unsigned short (*)[780])smem;
    int i = blockIdx.x, b = blockIdx.y, j0 = blockIdx.z * 32;
    int tid = threadIdx.x, lane = tid & 63, wave = tid >> 6;

    const uint2* ur = (const uint2*)(xb16 + ((size_t)b * XROWS + i) * 768);
    const uint2* pr = (const uint2*)(xb16 + ((size_t)b * XROWS + 256) * 768);
    const float4* lg4 = (const float4*)ln_g;
    const float4* lb4 = (const float4*)ln_b;
    float4 t1[3], gg[3], bb[3];
#pragma unroll
    for (int s = 0; s < 3; s++) {
        int c = lane + 64 * s;
        float4 x = unpk4(ur[c]), y = unpk4(pr[c]);
        t1[s] = make_float4(x.x + y.x, x.y + y.y, x.z + y.z, x.w + y.w);
        gg[s] = lg4[c];
        bb[s] = lb4[c];
    }

#pragma unroll
    for (int jj = 0; jj < 4; jj++) {
        int j = wave * 4 + jj;
        const uint2* vr2 = (const uint2*)(xb16 + ((size_t)b * XROWS + 128 + j0 + j) * 768);
        float4 z[3];
        float s1 = 0.f, s2 = 0.f;
#pragma unroll
        for (int s = 0; s < 3; s++) {
            float4 vv = unpk4(vr2[lane + 64 * s]);
            vv.x += t1[s].x; vv.y += t1[s].y; vv.z += t1[s].z; vv.w += t1[s].w;
            z[s] = vv;
            s1 += vv.x + vv.y + vv.z + vv.w;
            s2 += vv.x * vv.x + vv.y * vv.y + vv.z * vv.z + vv.w * vv.w;
        }
#pragma unroll
        for (int off = 32; off > 0; off >>= 1) {
            s1 += __shfl_xor(s1, off, 64);
            s2 += __shfl_xor(s2, off, 64);
        }
        float mu = s1 * (1.f / 768.f);
        float rs = rsqrtf(s2 * (1.f / 768.f) - mu * mu + LN_EPS);
        uint2* zrow = (uint2*)&zls[j][0];
#pragma unroll
        for (int s = 0; s < 3; s++) {
            float A0 = rs * gg[s].x, A1 = rs * gg[s].y, A2 = rs * gg[s].z, A3 = rs * gg[s].w;
            float C0 = fmaf(-mu, A0, bb[s].x), C1 = fmaf(-mu, A1, bb[s].y);
            float C2 = fmaf(-mu, A2, bb[s].z), C3 = fmaf(-mu, A3, bb[s].w);
            float z0 = fmaf(z[s].x, A0, C0);
            float z1 = fmaf(z[s].y, A1, C1);
            float z2 = fmaf(z[s].z, A2, C2);
            float z3 = fmaf(z[s].w, A3, C3);
            z0 = fmaxf(z0, __expf(fminf(z0, 0.f)) - 1.f);
            z1 = fmaxf(z1, __expf(fminf(z1, 0.f)) - 1.f);
            z2 = fmaxf(z2, __expf(fminf(z2, 0.f)) - 1.f);
            z3 = fmaxf(z3, __expf(fminf(z3, 0.f)) - 1.f);
            uint2 o;
            o.x = (unsigned)f2b(z0) | ((unsigned)f2b(z1) << 16);
            o.y = (unsigned)f2b(z2) | ((unsigned)f2b(z3) << 16);
            zrow[lane + 64 * s] = o;
        }
    }
    __syncthreads();

    // phase 2: wave kq handles K-steps kq*6..kq*6+5 of 48 (K=768, 16 per step)
    int arow = lane & 31, ahi = lane >> 5;
    f32x16 acc = {0.f,0.f,0.f,0.f, 0.f,0.f,0.f,0.f, 0.f,0.f,0.f,0.f, 0.f,0.f,0.f,0.f};
    const unsigned short* bptr = rwb2 + ((size_t)(wave * 6) * 64 + lane) * 8;
#pragma unroll
    for (int st = 0; st < 6; st++) {
        int s = wave * 6 + st;
        short8 a  = *(const short8*)&zls[arow][s * 16 + ahi * 8];
        short8 bf = *(const short8*)(bptr + (size_t)st * 512);
        acc = __builtin_amdgcn_mfma_f32_32x32x16_bf16(a, bf, acc, 0, 0, 0);
    }
    __syncthreads();
    float* pf = (float*)smem;                 // 8 waves x 1024 f32 = 32 KB
#pragma unroll
    for (int r = 0; r < 16; r++) {
        int row = (r & 3) + 8 * (r >> 2) + 4 * ahi;
        pf[wave * 1024 + row * 32 + arow] = acc[r];
    }
    __syncthreads();

#pragma unroll
    for (int e0 = 0; e0 < 2; e0++) {
        int e = tid + e0 * 512;
        int row = e >> 5, col = e & 31;
        if (col < 24) {
            float v = 0.f;
#pragma unroll
            for (int w = 0; w < 8; w++) v += pf[w * 1024 + e];
            int jgl = j0 + row;
            float mval = mask[i * 4 + b] * mask[jgl * 4 + b];
            out[((size_t)(i * 128 + jgl) * 4 + b) * 24 + col] =
                mval / (1.f + __expf(-(v + rel_b[col])));
        }
    }
}

// ---------------------------------------------------------------------------
extern "C" void kernel_launch(void* const* d_in, const int* in_sizes, int n_in,
                              void* d_out, int out_size, void* d_ws, size_t ws_size,
                              hipStream_t stream) {
    const float* h_re    = (const float*)d_in[0];
    const float* h_share = (const float*)d_in[1];
    const float* mask    = (const float*)d_in[2];
    const float* r_w     = (const float*)d_in[3];
    const float* r_b     = (const float*)d_in[4];
    const float* hid_w   = (const float*)d_in[5];
    const float* hid_b   = (const float*)d_in[6];
    const float* ln_g    = (const float*)d_in[7];
    const float* ln_b    = (const float*)d_in[8];
    const float* rel_w   = (const float*)d_in[9];
    const float* rel_b   = (const float*)d_in[10];
    float* out = (float*)d_out;

    float* ws = (float*)d_ws;
    unsigned short* apack  = (unsigned short*)(ws);             // 393216 f
    unsigned short* wpackA = (unsigned short*)(ws + 393216);    // 589824 f
    unsigned short* wpackB = (unsigned short*)(ws + 983040);    // 589824 f
    unsigned short* xb16   = (unsigned short*)(ws + 1572864);   // 417792 f
    unsigned int*   gmax   = (unsigned int*)(ws + 1990656);     // 3072
    unsigned short* rwb2   = (unsigned short*)(ws + 1993728);   // 12288 f

    kConv<<<1552, 256, 0, stream>>>(h_re, h_share, r_w, hid_w, rel_w,
                                    apack, wpackA, wpackB, rwb2, gmax);
    kGemm<<<1152, 256, 0, stream>>>(apack, wpackA, wpackB, gmax, xb16);
    kPg<<<dim3(12, 4), 256, 0, stream>>>(gmax, r_b, hid_w, hid_b, xb16);
    kC<<<dim3(L, B, 4), 512, 0, stream>>>(xb16, ln_g, ln_b, rwb2, rel_b,
                                          mask, out);
}

// Round 16
// 72.690 us; speedup vs baseline: 1.0435x; 1.0059x over previous
//
#include <hip/hip_runtime.h>
#include <hip/hip_bf16.h>
#include <math.h>

#define L 128
#define B 4
#define H 768
#define LN_EPS 1e-5f
#define XROWS 272            // xb16 rows: [p1:0..127 | (unused) | pg:256 | tail]

typedef __attribute__((ext_vector_type(8))) short short8;
typedef __attribute__((ext_vector_type(4))) float f32x4;

static __device__ __forceinline__ unsigned f2bfu(float f) {
    unsigned u = __float_as_uint(f);
    return (u + 0x7FFFu + ((u >> 16) & 1u)) >> 16;
}
static __device__ __forceinline__ uint2 pk4(float4 v) {
    uint2 o;
    o.x = f2bfu(v.x) | (f2bfu(v.y) << 16);
    o.y = f2bfu(v.z) | (f2bfu(v.w) << 16);
    return o;
}
static __device__ __forceinline__ unsigned short f2b(float f) {
    union { __hip_bfloat16 h; unsigned short u; } cv;
    cv.h = __float2bfloat16(f);
    return cv.u;
}
static __device__ __forceinline__ unsigned fkey(float x) {
    unsigned u = __float_as_uint(x);
    return (u >> 31) ? ~u : (u | 0x80000000u);
}

// ---------------------------------------------------------------------------
// kConv: all fp32->bf16 packing, coalesced READS + scattered 16B writes.
// rwb16: [2 nt][24 ks][64 lane][8] rel_w B-frags for 16x16x32 (r10-verified).
// ---------------------------------------------------------------------------
__global__ __launch_bounds__(256) void kConv(const float* __restrict__ h_re,
                                             const float* __restrict__ h_share,
                                             const float* __restrict__ r_w,
                                             const float* __restrict__ hid_w,
                                             const float* __restrict__ rel_w,
                                             unsigned short* __restrict__ apack,
                                             unsigned short* __restrict__ wpackA,
                                             unsigned short* __restrict__ wpackB,
                                             unsigned short* __restrict__ rwb16,
                                             unsigned int* __restrict__ gmax) {
    int t = blockIdx.x * 256 + threadIdx.x;
    if (t >= 397056) return;
    if (t < 98304) {                          // apack: Acat=[h_share|h_re]
        int m = t / 192, oct = t % 192, k = oct * 8;
        const float* src = (k < 768) ? (h_share + (size_t)m * 768 + k)
                                     : (h_re + (size_t)m * 768 + k - 768);
        float4 x = *(const float4*)src, y = *(const float4*)(src + 4);
        int mt = m >> 4, lr = m & 15, ks = k >> 5, lq = (k >> 3) & 3;
        uint2* dst = (uint2*)(apack + (((size_t)mt * 48 + ks) * 64 + lq * 16 + lr) * 8);
        dst[0] = pk4(x); dst[1] = pk4(y);
    } else if (t < 245760) {                  // wpackA: r_w rows
        int t2 = t - 98304;
        int n = t2 / 192, oct = t2 % 192, k = oct * 8;
        const float* src = r_w + (size_t)n * 1536 + k;
        float4 x = *(const float4*)src, y = *(const float4*)(src + 4);
        int nt = n >> 4, lr = n & 15, ks = k >> 5, lq = (k >> 3) & 3;
        uint2* dst = (uint2*)(wpackA + (((size_t)nt * 48 + ks) * 64 + lq * 16 + lr) * 8);
        dst[0] = pk4(x); dst[1] = pk4(y);
    } else if (t < 393216) {                  // wpackB: hid_w rows (w1|w2)
        int t3 = t - 245760;
        int n = t3 / 96, oct = t3 % 96, k = oct * 8;
        int half = (n >= 768) ? 1 : 0;
        const float* src = hid_w + (size_t)(n - half * 768) * 2304 + half * 768 + k;
        float4 x = *(const float4*)src, y = *(const float4*)(src + 4);
        int nt = n >> 4, lr = n & 15, ks = k >> 5, lq = (k >> 3) & 3;
        uint2* dst = (uint2*)(wpackB + (((size_t)nt * 24 + ks) * 64 + lq * 16 + lr) * 8);
        dst[0] = pk4(x); dst[1] = pk4(y);
    } else if (t < 396288) {                  // rwb16 B-frags (16x16x32), zero-pad r>=24
        int t4 = t - 393216;
        int nt = t4 / 1536, ks = (t4 / 64) % 24, l = t4 & 63;
        int row = nt * 16 + (l & 15);
        int k = ks * 32 + (l >> 4) * 8;
        uint2 o0 = make_uint2(0u, 0u), o1 = o0;
        if (row < 24) {
            const float* src = rel_w + (size_t)row * 768 + k;
            o0 = pk4(*(const float4*)src);
            o1 = pk4(*(const float4*)(src + 4));
        }
        uint2* dst = (uint2*)(rwb16 + (size_t)t4 * 8);
        dst[0] = o0; dst[1] = o1;
    } else {                                  // gmax zero (768 scalars)
        int t6 = t - 396288;
        gmax[t6] = 0u;
        gmax[768 + t6] = 0u;
        gmax[1536 + t6] = 0u;
        gmax[2304 + t6] = 0u;
    }
}

// ---------------------------------------------------------------------------
// kGemm: 4-wave blocks, one 32x32 tile per block, K split 4 ways across waves,
// LDS reduce, epilogue on wave 0. B-part now writes p2 into vpack (MFMA
// A-frag layout for kC): element (j,k) -> [b][j>>4][k>>5][((k>>3)&3)*16+(j&15)][k&7]
// ---------------------------------------------------------------------------
template<int KSW>
static __device__ __forceinline__ void gemm_steps(const unsigned short* __restrict__ a0p,
                                                  const unsigned short* __restrict__ a1p,
                                                  const unsigned short* __restrict__ w0p,
                                                  const unsigned short* __restrict__ w1p,
                                                  f32x4 acc[2][2]) {
#pragma unroll
    for (int s = 0; s < KSW; s++) {
        short8 a0 = *(const short8*)(a0p + (size_t)s * 512);
        short8 a1 = *(const short8*)(a1p + (size_t)s * 512);
        short8 w0 = *(const short8*)(w0p + (size_t)s * 512);
        short8 w1 = *(const short8*)(w1p + (size_t)s * 512);
        acc[0][0] = __builtin_amdgcn_mfma_f32_16x16x32_bf16(a0, w0, acc[0][0], 0, 0, 0);
        acc[0][1] = __builtin_amdgcn_mfma_f32_16x16x32_bf16(a0, w1, acc[0][1], 0, 0, 0);
        acc[1][0] = __builtin_amdgcn_mfma_f32_16x16x32_bf16(a1, w0, acc[1][0], 0, 0, 0);
        acc[1][1] = __builtin_amdgcn_mfma_f32_16x16x32_bf16(a1, w1, acc[1][1], 0, 0, 0);
    }
}

__global__ __launch_bounds__(256) void kGemm(const unsigned short* __restrict__ apack,
                                             const unsigned short* __restrict__ wpackA,
                                             const unsigned short* __restrict__ wpackB,
                                             unsigned int* __restrict__ gmax,
                                             unsigned short* __restrict__ xb16,
                                             unsigned short* __restrict__ vpack) {
    __shared__ float red[4][4][64][4];        // 16 KB
    int id = blockIdx.x;
    int tid = threadIdx.x, lane = tid & 63, wv = tid >> 6;
    int lq = lane >> 4, lr = lane & 15;
    bool isA = id < 384;
    f32x4 acc[2][2] = {{{0.f,0.f,0.f,0.f},{0.f,0.f,0.f,0.f}},
                       {{0.f,0.f,0.f,0.f},{0.f,0.f,0.f,0.f}}};
    int mt0, nt0;
    if (isA) {
        mt0 = (id / 24) * 2; nt0 = (id % 24) * 2;
        const unsigned short* a0p = apack + ((size_t)mt0 * 48 + wv * 12) * 512 + lane * 8;
        const unsigned short* w0p = wpackA + ((size_t)nt0 * 48 + wv * 12) * 512 + lane * 8;
        gemm_steps<12>(a0p, a0p + 48 * 512, w0p, w0p + 48 * 512, acc);
    } else {
        int id2 = id - 384;
        mt0 = (id2 / 48) * 2; nt0 = (id2 % 48) * 2;
        const unsigned short* a0p = apack + ((size_t)mt0 * 48 + 24 + wv * 6) * 512 + lane * 8;
        const unsigned short* w0p = wpackB + ((size_t)nt0 * 24 + wv * 6) * 512 + lane * 8;
        gemm_steps<6>(a0p, a0p + 48 * 512, w0p, w0p + 24 * 512, acc);
    }
#pragma unroll
    for (int mi = 0; mi < 2; mi++)
#pragma unroll
        for (int ni = 0; ni < 2; ni++)
            *(f32x4*)&red[wv][mi * 2 + ni][lane][0] = acc[mi][ni];
    __syncthreads();
    if (wv != 0) return;

    f32x4 s2[2][2];
#pragma unroll
    for (int mi = 0; mi < 2; mi++)
#pragma unroll
        for (int ni = 0; ni < 2; ni++) {
            f32x4 v = *(f32x4*)&red[0][mi * 2 + ni][lane][0];
#pragma unroll
            for (int w = 1; w < 4; w++) {
                f32x4 u = *(f32x4*)&red[w][mi * 2 + ni][lane][0];
                v[0] += u[0]; v[1] += u[1]; v[2] += u[2]; v[3] += u[3];
            }
            s2[mi][ni] = v;
        }

    if (isA) {
#pragma unroll
        for (int ni = 0; ni < 2; ni++)
#pragma unroll
            for (int q = 0; q < 4; q++) {
                float mx = fmaxf(s2[0][ni][q], s2[1][ni][q]);
                mx = fmaxf(mx, __shfl_xor(mx, 16, 64));
                mx = fmaxf(mx, __shfl_xor(mx, 32, 64));
                if (lq == 0) {
                    int n = (nt0 + ni) * 16 + lr;
                    atomicMax(&gmax[q * 768 + n], fkey(mx));
                }
            }
    } else {
#pragma unroll
        for (int mi = 0; mi < 2; mi++)
#pragma unroll
            for (int ni = 0; ni < 2; ni++)
#pragma unroll
                for (int q = 0; q < 4; q++) {
                    int m = (mt0 + mi) * 16 + lq * 4 + q;
                    int n = (nt0 + ni) * 16 + lr;
                    int b = m & 3, l = m >> 2;
                    unsigned short val = f2b(s2[mi][ni][q]);
                    if (n < 768) {
                        xb16[((size_t)b * XROWS + l) * 768 + n] = val;
                    } else {
                        int k = n - 768;
                        size_t dst = ((((size_t)(b * 8 + (l >> 4)) * 24) + (k >> 5)) * 64
                                      + ((k >> 3) & 3) * 16 + (l & 15)) * 8 + (k & 7);
                        vpack[dst] = val;
                    }
                }
    }
}

// ---------------------------------------------------------------------------
// kPg: decode gmax -> g = tanh(max+r_b), pg = g.w3 + hid_b -> xb16 row 256.
// ---------------------------------------------------------------------------
__global__ __launch_bounds__(256) void kPg(const unsigned int* __restrict__ gmax,
                                           const float* __restrict__ r_b,
                                           const float* __restrict__ hid_w,
                                           const float* __restrict__ hid_b,
                                           unsigned short* __restrict__ xb16) {
    __shared__ float sg[768];
    __shared__ float sp[4][64];
    int kt = blockIdx.x, b = blockIdx.y, tid = threadIdx.x;
    for (int v = tid; v < 768; v += 256) {
        unsigned key = gmax[b * 768 + v];
        unsigned bits = (key & 0x80000000u) ? (key & 0x7FFFFFFFu) : ~key;
        sg[v] = tanhf(__uint_as_float(bits) + r_b[v]);
    }
    __syncthreads();
    int kk = tid & 63, hc = tid >> 6;
    int k = kt * 64 + kk;
    const float4* w4 = (const float4*)hid_w;
    const float4* g4 = (const float4*)sg;
    float acc = 0.f;
    for (int h = hc * 48; h < hc * 48 + 48; h++) {
        float4 gv = g4[h];
        float4 wv = w4[(size_t)k * 576 + 384 + h];
        acc += gv.x * wv.x + gv.y * wv.y + gv.z * wv.z + gv.w * wv.w;
    }
    sp[hc][kk] = acc;
    __syncthreads();
    if (hc == 0) {
        float pgv = sp[0][kk] + sp[1][kk] + sp[2][kk] + sp[3][kk] + hid_b[k];
        xb16[((size_t)b * XROWS + 256) * 768 + k] = f2b(pgv);
    }
}

// ---------------------------------------------------------------------------
// kC v3: ZERO LDS, ZERO barriers. One wave owns one (i, b, 16-j) tile.
// Lane role: loads row lr = lane&15 of the tile, k-chunk lh = lane>>4.
// pass1: stream v(frag)+u+pg -> s1/s2; row reduce = 2 shfl_xor (4 lanes/row).
// pass2: re-stream (L1-hot), LN+ELU, pack short8, feed mfma_16x16x32 direct.
// Epilogue: C-frag (col=lane&15 -> r, row=(lane>>4)*4+q -> j) sigmoid+mask.
// grid (128, 4, 2) x 256 thr; wave w -> jg = z*4 + w (8 jg of 16 j).
// ---------------------------------------------------------------------------
__global__ __launch_bounds__(256) void kC(const unsigned short* __restrict__ xb16,
                                          const unsigned short* __restrict__ vpack,
                                          const float* __restrict__ ln_g,
                                          const float* __restrict__ ln_b,
                                          const unsigned short* __restrict__ rwb16,
                                          const float* __restrict__ rel_b,
                                          const float* __restrict__ mask,
                                          float* __restrict__ out) {
    int i = blockIdx.x, b = blockIdx.y;
    int tid = threadIdx.x, lane = tid & 63, wave = tid >> 6;
    int jg = blockIdx.z * 4 + wave;
    int lr = lane & 15, lh = lane >> 4;

    const unsigned short* p1r = xb16 + ((size_t)b * XROWS + i) * 768;
    const unsigned short* pgr = xb16 + ((size_t)b * XROWS + 256) * 768;
    const unsigned short* vfr = vpack + (((size_t)(b * 8 + jg) * 24) * 64 + (size_t)lane) * 8;

    // pass 1: stats of row j = jg*16 + lr
    float s1 = 0.f, s2 = 0.f;
    for (int s = 0; s < 24; s++) {
        int k = s * 32 + lh * 8;
        uint4 vv = *(const uint4*)(vfr + (size_t)s * 512);
        uint4 uu = *(const uint4*)(p1r + k);
        uint4 pp = *(const uint4*)(pgr + k);
        const unsigned* vw = (const unsigned*)&vv;
        const unsigned* uw = (const unsigned*)&uu;
        const unsigned* pw = (const unsigned*)&pp;
#pragma unroll
        for (int h = 0; h < 4; h++) {
            float z0 = __uint_as_float(vw[h] << 16) + __uint_as_float(uw[h] << 16)
                     + __uint_as_float(pw[h] << 16);
            float z1 = __uint_as_float(vw[h] & 0xffff0000u) + __uint_as_float(uw[h] & 0xffff0000u)
                     + __uint_as_float(pw[h] & 0xffff0000u);
            s1 += z0 + z1;
            s2 = fmaf(z0, z0, fmaf(z1, z1, s2));
        }
    }
    s1 += __shfl_xor(s1, 16, 64); s1 += __shfl_xor(s1, 32, 64);
    s2 += __shfl_xor(s2, 16, 64); s2 += __shfl_xor(s2, 32, 64);
    float mu  = s1 * (1.f / 768.f);
    float rs  = rsqrtf(s2 * (1.f / 768.f) - mu * mu + LN_EPS);
    float nmr = -mu * rs;

    // pass 2: LN + ELU + MFMA
    f32x4 acc0 = {0.f, 0.f, 0.f, 0.f}, acc1 = {0.f, 0.f, 0.f, 0.f};
    for (int s = 0; s < 24; s++) {
        int k = s * 32 + lh * 8;
        uint4 vv = *(const uint4*)(vfr + (size_t)s * 512);
        uint4 uu = *(const uint4*)(p1r + k);
        uint4 pp = *(const uint4*)(pgr + k);
        float4 g0 = *(const float4*)(ln_g + k), g1 = *(const float4*)(ln_g + k + 4);
        float4 b0 = *(const float4*)(ln_b + k), b1 = *(const float4*)(ln_b + k + 4);
        const unsigned* vw = (const unsigned*)&vv;
        const unsigned* uw = (const unsigned*)&uu;
        const unsigned* pw = (const unsigned*)&pp;
        float ge[8] = {g0.x, g0.y, g0.z, g0.w, g1.x, g1.y, g1.z, g1.w};
        float be[8] = {b0.x, b0.y, b0.z, b0.w, b1.x, b1.y, b1.z, b1.w};
        short8 a;
#pragma unroll
        for (int h = 0; h < 4; h++) {
            float z0 = __uint_as_float(vw[h] << 16) + __uint_as_float(uw[h] << 16)
                     + __uint_as_float(pw[h] << 16);
            float z1 = __uint_as_float(vw[h] & 0xffff0000u) + __uint_as_float(uw[h] & 0xffff0000u)
                     + __uint_as_float(pw[h] & 0xffff0000u);
            float t0 = fmaf(fmaf(z0, rs, nmr), ge[2 * h], be[2 * h]);
            float t1 = fmaf(fmaf(z1, rs, nmr), ge[2 * h + 1], be[2 * h + 1]);
            t0 = fmaxf(t0, __expf(fminf(t0, 0.f)) - 1.f);
            t1 = fmaxf(t1, __expf(fminf(t1, 0.f)) - 1.f);
            a[2 * h]     = (short)f2b(t0);
            a[2 * h + 1] = (short)f2b(t1);
        }
        short8 bf0 = *(const short8*)(rwb16 + ((size_t)s * 64 + lane) * 8);
        short8 bf1 = *(const short8*)(rwb16 + ((size_t)(24 + s) * 64 + lane) * 8);
        acc0 = __builtin_amdgcn_mfma_f32_16x16x32_bf16(a, bf0, acc0, 0, 0, 0);
        acc1 = __builtin_amdgcn_mfma_f32_16x16x32_bf16(a, bf1, acc1, 0, 0, 0);
    }

    float mi_ = mask[i * 4 + b];
#pragma unroll
    for (int q = 0; q < 4; q++) {
        int jglob = jg * 16 + lh * 4 + q;
        float mval = mi_ * mask[jglob * 4 + b];
        size_t ob = ((size_t)(i * 128 + jglob) * 4 + b) * 24;
        out[ob + lr] = mval / (1.f + __expf(-(acc0[q] + rel_b[lr])));
        if (lr < 8)
            out[ob + 16 + lr] = mval / (1.f + __expf(-(acc1[q] + rel_b[16 + lr])));
    }
}

// ---------------------------------------------------------------------------
extern "C" void kernel_launch(void* const* d_in, const int* in_sizes, int n_in,
                              void* d_out, int out_size, void* d_ws, size_t ws_size,
                              hipStream_t stream) {
    const float* h_re    = (const float*)d_in[0];
    const float* h_share = (const float*)d_in[1];
    const float* mask    = (const float*)d_in[2];
    const float* r_w     = (const float*)d_in[3];
    const float* r_b     = (const float*)d_in[4];
    const float* hid_w   = (const float*)d_in[5];
    const float* hid_b   = (const float*)d_in[6];
    const float* ln_g    = (const float*)d_in[7];
    const float* ln_b    = (const float*)d_in[8];
    const float* rel_w   = (const float*)d_in[9];
    const float* rel_b   = (const float*)d_in[10];
    float* out = (float*)d_out;

    float* ws = (float*)d_ws;
    unsigned short* apack  = (unsigned short*)(ws);             // 393216 f
    unsigned short* wpackA = (unsigned short*)(ws + 393216);    // 589824 f
    unsigned short* wpackB = (unsigned short*)(ws + 983040);    // 589824 f
    unsigned short* xb16   = (unsigned short*)(ws + 1572864);   // 417792 f
    unsigned short* vpack  = (unsigned short*)(ws + 1990656);   // 196608 f
    unsigned int*   gmax   = (unsigned int*)(ws + 2187264);     // 3072
    unsigned short* rwb16  = (unsigned short*)(ws + 2190336);   // 12288 f

    kConv<<<1552, 256, 0, stream>>>(h_re, h_share, r_w, hid_w, rel_w,
                                    apack, wpackA, wpackB, rwb16, gmax);
    kGemm<<<1152, 256, 0, stream>>>(apack, wpackA, wpackB, gmax, xb16, vpack);
    kPg<<<dim3(12, 4), 256, 0, stream>>>(gmax, r_b, hid_w, hid_b, xb16);
    kC<<<dim3(128, 4, 2), 256, 0, stream>>>(xb16, vpack, ln_g, ln_b, rwb16,
                                            rel_b, mask, out);
}

// Round 17
// 70.525 us; speedup vs baseline: 1.0755x; 1.0307x over previous
//
#include <hip/hip_runtime.h>
#include <hip/hip_bf16.h>
#include <math.h>

#define L 128
#define B 4
#define H 768
#define LN_EPS 1e-5f
#define XROWS 272            // xb16 rows: [p1:0..127 | (unused) | pg:256 | tail]

typedef __attribute__((ext_vector_type(8))) short short8;
typedef __attribute__((ext_vector_type(4))) float f32x4;

static __device__ __forceinline__ unsigned f2bfu(float f) {
    unsigned u = __float_as_uint(f);
    return (u + 0x7FFFu + ((u >> 16) & 1u)) >> 16;
}
static __device__ __forceinline__ uint2 pk4(float4 v) {
    uint2 o;
    o.x = f2bfu(v.x) | (f2bfu(v.y) << 16);
    o.y = f2bfu(v.z) | (f2bfu(v.w) << 16);
    return o;
}
static __device__ __forceinline__ unsigned short f2b(float f) {
    union { __hip_bfloat16 h; unsigned short u; } cv;
    cv.h = __float2bfloat16(f);
    return cv.u;
}
static __device__ __forceinline__ unsigned fkey(float x) {
    unsigned u = __float_as_uint(x);
    return (u >> 31) ? ~u : (u | 0x80000000u);
}

// ---------------------------------------------------------------------------
// kConv: all fp32->bf16 packing, coalesced READS + scattered 16B writes.
// ---------------------------------------------------------------------------
__global__ __launch_bounds__(256) void kConv(const float* __restrict__ h_re,
                                             const float* __restrict__ h_share,
                                             const float* __restrict__ r_w,
                                             const float* __restrict__ hid_w,
                                             const float* __restrict__ rel_w,
                                             unsigned short* __restrict__ apack,
                                             unsigned short* __restrict__ wpackA,
                                             unsigned short* __restrict__ wpackB,
                                             unsigned short* __restrict__ rwb16,
                                             unsigned int* __restrict__ gmax) {
    int t = blockIdx.x * 256 + threadIdx.x;
    if (t >= 397056) return;
    if (t < 98304) {                          // apack: Acat=[h_share|h_re]
        int m = t / 192, oct = t % 192, k = oct * 8;
        const float* src = (k < 768) ? (h_share + (size_t)m * 768 + k)
                                     : (h_re + (size_t)m * 768 + k - 768);
        float4 x = *(const float4*)src, y = *(const float4*)(src + 4);
        int mt = m >> 4, lr = m & 15, ks = k >> 5, lq = (k >> 3) & 3;
        uint2* dst = (uint2*)(apack + (((size_t)mt * 48 + ks) * 64 + lq * 16 + lr) * 8);
        dst[0] = pk4(x); dst[1] = pk4(y);
    } else if (t < 245760) {                  // wpackA: r_w rows
        int t2 = t - 98304;
        int n = t2 / 192, oct = t2 % 192, k = oct * 8;
        const float* src = r_w + (size_t)n * 1536 + k;
        float4 x = *(const float4*)src, y = *(const float4*)(src + 4);
        int nt = n >> 4, lr = n & 15, ks = k >> 5, lq = (k >> 3) & 3;
        uint2* dst = (uint2*)(wpackA + (((size_t)nt * 48 + ks) * 64 + lq * 16 + lr) * 8);
        dst[0] = pk4(x); dst[1] = pk4(y);
    } else if (t < 393216) {                  // wpackB: hid_w rows (w1|w2)
        int t3 = t - 245760;
        int n = t3 / 96, oct = t3 % 96, k = oct * 8;
        int half = (n >= 768) ? 1 : 0;
        const float* src = hid_w + (size_t)(n - half * 768) * 2304 + half * 768 + k;
        float4 x = *(const float4*)src, y = *(const float4*)(src + 4);
        int nt = n >> 4, lr = n & 15, ks = k >> 5, lq = (k >> 3) & 3;
        uint2* dst = (uint2*)(wpackB + (((size_t)nt * 24 + ks) * 64 + lq * 16 + lr) * 8);
        dst[0] = pk4(x); dst[1] = pk4(y);
    } else if (t < 396288) {                  // rwb16 B-frags (16x16x32), zero-pad r>=24
        int t4 = t - 393216;
        int nt = t4 / 1536, ks = (t4 / 64) % 24, l = t4 & 63;
        int row = nt * 16 + (l & 15);
        int k = ks * 32 + (l >> 4) * 8;
        uint2 o0 = make_uint2(0u, 0u), o1 = o0;
        if (row < 24) {
            const float* src = rel_w + (size_t)row * 768 + k;
            o0 = pk4(*(const float4*)src);
            o1 = pk4(*(const float4*)(src + 4));
        }
        uint2* dst = (uint2*)(rwb16 + (size_t)t4 * 8);
        dst[0] = o0; dst[1] = o1;
    } else {                                  // gmax zero (768 scalars)
        int t6 = t - 396288;
        gmax[t6] = 0u;
        gmax[768 + t6] = 0u;
        gmax[1536 + t6] = 0u;
        gmax[2304 + t6] = 0u;
    }
}

// ---------------------------------------------------------------------------
// kGemm: 4-wave blocks, one 32x32 tile per block, K split 4 ways across waves,
// LDS reduce, epilogue on wave 0. B-part writes p2 into vpack (MFMA A-frag
// layout for kC).
// ---------------------------------------------------------------------------
template<int KSW>
static __device__ __forceinline__ void gemm_steps(const unsigned short* __restrict__ a0p,
                                                  const unsigned short* __restrict__ a1p,
                                                  const unsigned short* __restrict__ w0p,
                                                  const unsigned short* __restrict__ w1p,
                                                  f32x4 acc[2][2]) {
#pragma unroll
    for (int s = 0; s < KSW; s++) {
        short8 a0 = *(const short8*)(a0p + (size_t)s * 512);
        short8 a1 = *(const short8*)(a1p + (size_t)s * 512);
        short8 w0 = *(const short8*)(w0p + (size_t)s * 512);
        short8 w1 = *(const short8*)(w1p + (size_t)s * 512);
        acc[0][0] = __builtin_amdgcn_mfma_f32_16x16x32_bf16(a0, w0, acc[0][0], 0, 0, 0);
        acc[0][1] = __builtin_amdgcn_mfma_f32_16x16x32_bf16(a0, w1, acc[0][1], 0, 0, 0);
        acc[1][0] = __builtin_amdgcn_mfma_f32_16x16x32_bf16(a1, w0, acc[1][0], 0, 0, 0);
        acc[1][1] = __builtin_amdgcn_mfma_f32_16x16x32_bf16(a1, w1, acc[1][1], 0, 0, 0);
    }
}

__global__ __launch_bounds__(256) void kGemm(const unsigned short* __restrict__ apack,
                                             const unsigned short* __restrict__ wpackA,
                                             const unsigned short* __restrict__ wpackB,
                                             unsigned int* __restrict__ gmax,
                                             unsigned short* __restrict__ xb16,
                                             unsigned short* __restrict__ vpack) {
    __shared__ float red[4][4][64][4];        // 16 KB
    int id = blockIdx.x;
    int tid = threadIdx.x, lane = tid & 63, wv = tid >> 6;
    int lq = lane >> 4, lr = lane & 15;
    bool isA = id < 384;
    f32x4 acc[2][2] = {{{0.f,0.f,0.f,0.f},{0.f,0.f,0.f,0.f}},
                       {{0.f,0.f,0.f,0.f},{0.f,0.f,0.f,0.f}}};
    int mt0, nt0;
    if (isA) {
        mt0 = (id / 24) * 2; nt0 = (id % 24) * 2;
        const unsigned short* a0p = apack + ((size_t)mt0 * 48 + wv * 12) * 512 + lane * 8;
        const unsigned short* w0p = wpackA + ((size_t)nt0 * 48 + wv * 12) * 512 + lane * 8;
        gemm_steps<12>(a0p, a0p + 48 * 512, w0p, w0p + 48 * 512, acc);
    } else {
        int id2 = id - 384;
        mt0 = (id2 / 48) * 2; nt0 = (id2 % 48) * 2;
        const unsigned short* a0p = apack + ((size_t)mt0 * 48 + 24 + wv * 6) * 512 + lane * 8;
        const unsigned short* w0p = wpackB + ((size_t)nt0 * 24 + wv * 6) * 512 + lane * 8;
        gemm_steps<6>(a0p, a0p + 48 * 512, w0p, w0p + 24 * 512, acc);
    }
#pragma unroll
    for (int mi = 0; mi < 2; mi++)
#pragma unroll
        for (int ni = 0; ni < 2; ni++)
            *(f32x4*)&red[wv][mi * 2 + ni][lane][0] = acc[mi][ni];
    __syncthreads();
    if (wv != 0) return;

    f32x4 s2[2][2];
#pragma unroll
    for (int mi = 0; mi < 2; mi++)
#pragma unroll
        for (int ni = 0; ni < 2; ni++) {
            f32x4 v = *(f32x4*)&red[0][mi * 2 + ni][lane][0];
#pragma unroll
            for (int w = 1; w < 4; w++) {
                f32x4 u = *(f32x4*)&red[w][mi * 2 + ni][lane][0];
                v[0] += u[0]; v[1] += u[1]; v[2] += u[2]; v[3] += u[3];
            }
            s2[mi][ni] = v;
        }

    if (isA) {
#pragma unroll
        for (int ni = 0; ni < 2; ni++)
#pragma unroll
            for (int q = 0; q < 4; q++) {
                float mx = fmaxf(s2[0][ni][q], s2[1][ni][q]);
                mx = fmaxf(mx, __shfl_xor(mx, 16, 64));
                mx = fmaxf(mx, __shfl_xor(mx, 32, 64));
                if (lq == 0) {
                    int n = (nt0 + ni) * 16 + lr;
                    atomicMax(&gmax[q * 768 + n], fkey(mx));
                }
            }
    } else {
#pragma unroll
        for (int mi = 0; mi < 2; mi++)
#pragma unroll
            for (int ni = 0; ni < 2; ni++)
#pragma unroll
                for (int q = 0; q < 4; q++) {
                    int m = (mt0 + mi) * 16 + lq * 4 + q;
                    int n = (nt0 + ni) * 16 + lr;
                    int b = m & 3, l = m >> 2;
                    unsigned short val = f2b(s2[mi][ni][q]);
                    if (n < 768) {
                        xb16[((size_t)b * XROWS + l) * 768 + n] = val;
                    } else {
                        int k = n - 768;
                        size_t dst = ((((size_t)(b * 8 + (l >> 4)) * 24) + (k >> 5)) * 64
                                      + ((k >> 3) & 3) * 16 + (l & 15)) * 8 + (k & 7);
                        vpack[dst] = val;
                    }
                }
    }
}

// ---------------------------------------------------------------------------
// kPg: decode gmax -> g = tanh(max+r_b), pg = g.w3 + hid_b -> xb16 row 256.
// ---------------------------------------------------------------------------
__global__ __launch_bounds__(256) void kPg(const unsigned int* __restrict__ gmax,
                                           const float* __restrict__ r_b,
                                           const float* __restrict__ hid_w,
                                           const float* __restrict__ hid_b,
                                           unsigned short* __restrict__ xb16) {
    __shared__ float sg[768];
    __shared__ float sp[4][64];
    int kt = blockIdx.x, b = blockIdx.y, tid = threadIdx.x;
    for (int v = tid; v < 768; v += 256) {
        unsigned key = gmax[b * 768 + v];
        unsigned bits = (key & 0x80000000u) ? (key & 0x7FFFFFFFu) : ~key;
        sg[v] = tanhf(__uint_as_float(bits) + r_b[v]);
    }
    __syncthreads();
    int kk = tid & 63, hc = tid >> 6;
    int k = kt * 64 + kk;
    const float4* w4 = (const float4*)hid_w;
    const float4* g4 = (const float4*)sg;
    float acc = 0.f;
    for (int h = hc * 48; h < hc * 48 + 48; h++) {
        float4 gv = g4[h];
        float4 wv = w4[(size_t)k * 576 + 384 + h];
        acc += gv.x * wv.x + gv.y * wv.y + gv.z * wv.z + gv.w * wv.w;
    }
    sp[hc][kk] = acc;
    __syncthreads();
    if (hc == 0) {
        float pgv = sp[0][kk] + sp[1][kk] + sp[2][kk] + sp[3][kk] + hid_b[k];
        xb16[((size_t)b * XROWS + 256) * 768 + k] = f2b(pgv);
    }
}

// ---------------------------------------------------------------------------
// kC v4: zero LDS/barriers; 1-wave blocks, grid (128,4,8) -> 4096 blocks.
// __launch_bounds__(64,4): VGPR cap 128 (grid supplies 4 waves/SIMD) so the
// compiler can software-pipeline the 24-step loops (r16's 36-VGPR build
// couldn't prefetch -> 13 cyc/inst stall-bound).
// ---------------------------------------------------------------------------
__global__ __launch_bounds__(64, 4) void kC(const unsigned short* __restrict__ xb16,
                                            const unsigned short* __restrict__ vpack,
                                            const float* __restrict__ ln_g,
                                            const float* __restrict__ ln_b,
                                            const unsigned short* __restrict__ rwb16,
                                            const float* __restrict__ rel_b,
                                            const float* __restrict__ mask,
                                            float* __restrict__ out) {
    int i = blockIdx.x, b = blockIdx.y, jg = blockIdx.z;
    int lane = threadIdx.x;
    int lr = lane & 15, lh = lane >> 4;

    const unsigned short* p1r = xb16 + ((size_t)b * XROWS + i) * 768;
    const unsigned short* pgr = xb16 + ((size_t)b * XROWS + 256) * 768;
    const unsigned short* vfr = vpack + (((size_t)(b * 8 + jg) * 24) * 64 + (size_t)lane) * 8;

    // pass 1: stats of row j = jg*16 + lr
    float s1 = 0.f, s2 = 0.f;
#pragma unroll 4
    for (int s = 0; s < 24; s++) {
        int k = s * 32 + lh * 8;
        uint4 vv = *(const uint4*)(vfr + (size_t)s * 512);
        uint4 uu = *(const uint4*)(p1r + k);
        uint4 pp = *(const uint4*)(pgr + k);
        const unsigned* vw = (const unsigned*)&vv;
        const unsigned* uw = (const unsigned*)&uu;
        const unsigned* pw = (const unsigned*)&pp;
#pragma unroll
        for (int h = 0; h < 4; h++) {
            float z0 = __uint_as_float(vw[h] << 16) + __uint_as_float(uw[h] << 16)
                     + __uint_as_float(pw[h] << 16);
            float z1 = __uint_as_float(vw[h] & 0xffff0000u) + __uint_as_float(uw[h] & 0xffff0000u)
                     + __uint_as_float(pw[h] & 0xffff0000u);
            s1 += z0 + z1;
            s2 = fmaf(z0, z0, fmaf(z1, z1, s2));
        }
    }
    s1 += __shfl_xor(s1, 16, 64); s1 += __shfl_xor(s1, 32, 64);
    s2 += __shfl_xor(s2, 16, 64); s2 += __shfl_xor(s2, 32, 64);
    float mu  = s1 * (1.f / 768.f);
    float rs  = rsqrtf(s2 * (1.f / 768.f) - mu * mu + LN_EPS);
    float nmr = -mu * rs;

    // pass 2: LN + ELU + MFMA (L1-hot re-stream)
    f32x4 acc0 = {0.f, 0.f, 0.f, 0.f}, acc1 = {0.f, 0.f, 0.f, 0.f};
#pragma unroll 2
    for (int s = 0; s < 24; s++) {
        int k = s * 32 + lh * 8;
        uint4 vv = *(const uint4*)(vfr + (size_t)s * 512);
        uint4 uu = *(const uint4*)(p1r + k);
        uint4 pp = *(const uint4*)(pgr + k);
        float4 g0 = *(const float4*)(ln_g + k), g1 = *(const float4*)(ln_g + k + 4);
        float4 b0 = *(const float4*)(ln_b + k), b1 = *(const float4*)(ln_b + k + 4);
        const unsigned* vw = (const unsigned*)&vv;
        const unsigned* uw = (const unsigned*)&uu;
        const unsigned* pw = (const unsigned*)&pp;
        float ge[8] = {g0.x, g0.y, g0.z, g0.w, g1.x, g1.y, g1.z, g1.w};
        float be[8] = {b0.x, b0.y, b0.z, b0.w, b1.x, b1.y, b1.z, b1.w};
        short8 a;
#pragma unroll
        for (int h = 0; h < 4; h++) {
            float z0 = __uint_as_float(vw[h] << 16) + __uint_as_float(uw[h] << 16)
                     + __uint_as_float(pw[h] << 16);
            float z1 = __uint_as_float(vw[h] & 0xffff0000u) + __uint_as_float(uw[h] & 0xffff0000u)
                     + __uint_as_float(pw[h] & 0xffff0000u);
            float t0 = fmaf(fmaf(z0, rs, nmr), ge[2 * h], be[2 * h]);
            float t1 = fmaf(fmaf(z1, rs, nmr), ge[2 * h + 1], be[2 * h + 1]);
            t0 = fmaxf(t0, __expf(fminf(t0, 0.f)) - 1.f);
            t1 = fmaxf(t1, __expf(fminf(t1, 0.f)) - 1.f);
            a[2 * h]     = (short)f2b(t0);
            a[2 * h + 1] = (short)f2b(t1);
        }
        short8 bf0 = *(const short8*)(rwb16 + ((size_t)s * 64 + lane) * 8);
        short8 bf1 = *(const short8*)(rwb16 + ((size_t)(24 + s) * 64 + lane) * 8);
        acc0 = __builtin_amdgcn_mfma_f32_16x16x32_bf16(a, bf0, acc0, 0, 0, 0);
        acc1 = __builtin_amdgcn_mfma_f32_16x16x32_bf16(a, bf1, acc1, 0, 0, 0);
    }

    float mi_ = mask[i * 4 + b];
#pragma unroll
    for (int q = 0; q < 4; q++) {
        int jglob = jg * 16 + lh * 4 + q;
        float mval = mi_ * mask[jglob * 4 + b];
        size_t ob = ((size_t)(i * 128 + jglob) * 4 + b) * 24;
        out[ob + lr] = mval / (1.f + __expf(-(acc0[q] + rel_b[lr])));
        if (lr < 8)
            out[ob + 16 + lr] = mval / (1.f + __expf(-(acc1[q] + rel_b[16 + lr])));
    }
}

// ---------------------------------------------------------------------------
extern "C" void kernel_launch(void* const* d_in, const int* in_sizes, int n_in,
                              void* d_out, int out_size, void* d_ws, size_t ws_size,
                              hipStream_t stream) {
    const float* h_re    = (const float*)d_in[0];
    const float* h_share = (const float*)d_in[1];
    const float* mask    = (const float*)d_in[2];
    const float* r_w     = (const float*)d_in[3];
    const float* r_b     = (const float*)d_in[4];
    const float* hid_w   = (const float*)d_in[5];
    const float* hid_b   = (const float*)d_in[6];
    const float* ln_g    = (const float*)d_in[7];
    const float* ln_b    = (const float*)d_in[8];
    const float* rel_w   = (const float*)d_in[9];
    const float* rel_b   = (const float*)d_in[10];
    float* out = (float*)d_out;

    float* ws = (float*)d_ws;
    unsigned short* apack  = (unsigned short*)(ws);             // 393216 f
    unsigned short* wpackA = (unsigned short*)(ws + 393216);    // 589824 f
    unsigned short* wpackB = (unsigned short*)(ws + 983040);    // 589824 f
    unsigned short* xb16   = (unsigned short*)(ws + 1572864);   // 417792 f
    unsigned short* vpack  = (unsigned short*)(ws + 1990656);   // 196608 f
    unsigned int*   gmax   = (unsigned int*)(ws + 2187264);     // 3072
    unsigned short* rwb16  = (unsigned short*)(ws + 2190336);   // 12288 f

    kConv<<<1552, 256, 0, stream>>>(h_re, h_share, r_w, hid_w, rel_w,
                                    apack, wpackA, wpackB, rwb16, gmax);
    kGemm<<<1152, 256, 0, stream>>>(apack, wpackA, wpackB, gmax, xb16, vpack);
    kPg<<<dim3(12, 4), 256, 0, stream>>>(gmax, r_b, hid_w, hid_b, xb16);
    kC<<<dim3(128, 4, 8), 64, 0, stream>>>(xb16, vpack, ln_g, ln_b, rwb16,
                                           rel_b, mask, out);
}